// Round 22
// baseline (101.757 us; speedup 1.0000x reference)
//
#include <hip/hip_runtime.h>

#define E_   1024
#define H_   16
#define DK_  64
#define FFN_ 4096
#define NQ_  8
#define B_   2
#define T_   2048
#define QBLK 128
#define KVBLK 64
#define NT_  (T_ / KVBLK)

#define NPART 256
#define ROWS_PER_PART (FFN_ / NPART)   // 16
#define CVT_BLOCKS (B_ * (T_ / 64) * H_)   // 1024

typedef __attribute__((ext_vector_type(8))) __bf16 bf16x8;
typedef __attribute__((ext_vector_type(2))) __bf16 bf16x2;
typedef __attribute__((ext_vector_type(2))) float f32x2;
typedef __attribute__((ext_vector_type(4))) float f32x4;

__device__ __forceinline__ __bf16 tobf(float f) { return (__bf16)f; }

__device__ __forceinline__ unsigned pk2(float a, float b) {
  f32x2 f; f[0] = a; f[1] = b;
  bf16x2 h = __builtin_convertvector(f, bf16x2);   // v_cvt_pk_bf16_f32
  union { bf16x2 h; unsigned u; } u; u.h = h;
  return u.u;
}

// ---------------------------------------------------------------------------
// Kernel 0 (fat): blocks [0,1024): convert+transpose x -> xbf, xbfT;
//                 blocks [1024,1280): ffn_part (const-FFN split-K partials).
// ---------------------------------------------------------------------------
__global__ __launch_bounds__(256)
void prep_kernel(const float* __restrict__ x, __bf16* __restrict__ xbf,
                 __bf16* __restrict__ xbfT,
                 const float* __restrict__ q_out, const float* __restrict__ w1,
                 const float* __restrict__ b1, const float* __restrict__ w2,
                 float* __restrict__ part) {
  const int tid = threadIdx.x;
  if (blockIdx.x < CVT_BLOCKS) {
    __shared__ __bf16 tile[64][66];
    const int bid = blockIdx.x;
    const int h  = bid & 15;
    const int tt = (bid >> 4) & 31;
    const int b  = bid >> 9;
    const float* src = x + ((size_t)(b * T_ + tt * 64)) * E_ + h * 64;
#pragma unroll
    for (int u = 0; u < 2; ++u) {
      const int idx = tid + 256 * u;
      const int r = idx >> 3;
      const int c = (idx & 7) * 8;
      float4 f0 = *reinterpret_cast<const float4*>(src + (size_t)r * E_ + c);
      float4 f1 = *reinterpret_cast<const float4*>(src + (size_t)r * E_ + c + 4);
      bf16x8 v;
      v[0] = tobf(f0.x); v[1] = tobf(f0.y); v[2] = tobf(f0.z); v[3] = tobf(f0.w);
      v[4] = tobf(f1.x); v[5] = tobf(f1.y); v[6] = tobf(f1.z); v[7] = tobf(f1.w);
      *reinterpret_cast<bf16x8*>(
          &xbf[((size_t)(b * T_ + tt * 64 + r)) * E_ + h * 64 + c]) = v;
#pragma unroll
      for (int j = 0; j < 8; ++j) tile[r][c + j] = v[j];
    }
    __syncthreads();
#pragma unroll
    for (int u = 0; u < 2; ++u) {
      const int idx = tid + 256 * u;
      const int d  = idx >> 3;
      const int tc = (idx & 7) * 8;
      bf16x8 v;
#pragma unroll
      for (int j = 0; j < 8; ++j) v[j] = tile[tc + j][d];
      *reinterpret_cast<bf16x8*>(
          &xbfT[((size_t)((b * H_ + h) * DK_ + d)) * T_ + tt * 64 + tc]) = v;
    }
  } else {
    __shared__ float hbuf[ROWS_PER_PART];
    const int p = blockIdx.x - CVT_BLOCKS;
    const int f0 = p * ROWS_PER_PART;
    if (tid < ROWS_PER_PART) {
      const int f = f0 + tid;
      float a = b1[f];
#pragma unroll
      for (int n = 0; n < NQ_; ++n) a += q_out[n] * w1[n * FFN_ + f];
      hbuf[tid] = fmaxf(a, 0.f);
    }
    __syncthreads();
    float4 acc = {0.f, 0.f, 0.f, 0.f};
#pragma unroll
    for (int j = 0; j < ROWS_PER_PART; ++j) {
      const float hf = hbuf[j];
      float4 w = reinterpret_cast<const float4*>(w2 + (size_t)(f0 + j) * E_)[tid];
      acc.x += hf * w.x; acc.y += hf * w.y; acc.z += hf * w.z; acc.w += hf * w.w;
    }
    reinterpret_cast<float4*>(part + (size_t)p * E_)[tid] = acc;
  }
}

__global__ __launch_bounds__(256)
void ffn_reduce_kernel(const float* __restrict__ part, const float* __restrict__ b2,
                       float* __restrict__ ffn_c) {
  const int e = blockIdx.x * 256 + threadIdx.x;
  float a = b2[e];
  for (int r = 0; r < NPART; ++r) a += part[(size_t)r * E_ + e];
  ffn_c[e] = a;
}

// ---------------------------------------------------------------------------
// Kernel 2: flash attention (r16-verified structure).  Swapped QK^T, G=2
// (32 q-rows/wave sharing K/V fragment reads), Kt+VtF double-buffered
// (1 barrier/tile), V staged from xbfT (pure b128 copies), T14
// issue-early/write-late, setprio.  Softmax: exp2-folded + v_cvt_pk pack
// (r19-verified numerics).  grid = (T/128, B*H) x 256 thr.
// ---------------------------------------------------------------------------
__global__ __launch_bounds__(256)
void attn_kernel(const __bf16* __restrict__ xbf, const __bf16* __restrict__ xbfT,
                 float* __restrict__ out) {
  __shared__ __bf16 Kt[2][KVBLK][DK_ + 8];   // [buf][key][d]
  __shared__ __bf16 VtF[2][DK_ * KVBLK];     // [buf][d][key], byte^=(rot(d)<<4)
  __shared__ __bf16 Pl[4][32][DK_ + 8];      // per-wave P [qrow 0..31][key]

  const int tid  = threadIdx.x;
  const int wave = tid >> 6;
  const int lane = tid & 63;
  const int l16  = lane & 15;
  const int lhi  = lane >> 4;          // 0..3

  const int bh = blockIdx.y;
  const int b  = bh >> 4;
  const int h  = bh & 15;
  const int qbase = blockIdx.x * QBLK;
  const __bf16* xb = xbf + (size_t)b * T_ * E_ + h * DK_;

  // Q B-frags for 2 groups of 16 rows, scaled by 0.125*log2e (exp2 path)
  bf16x8 qa[2][2];
  {
    const float sc = 0.125f * 1.44269504088896f;
#pragma unroll
    for (int g = 0; g < 2; ++g) {
      const __bf16* qrow = xb + (size_t)(qbase + wave * 32 + g * 16 + l16) * E_;
      bf16x8 v0 = *reinterpret_cast<const bf16x8*>(qrow + lhi * 8);
      bf16x8 v1 = *reinterpret_cast<const bf16x8*>(qrow + 32 + lhi * 8);
#pragma unroll
      for (int j = 0; j < 8; ++j) {
        v0[j] = tobf((float)v0[j] * sc);
        v1[j] = tobf((float)v1[j] * sc);
      }
      qa[g][0] = v0; qa[g][1] = v1;
    }
  }

  f32x4 acc[2][4];
#pragma unroll
  for (int g = 0; g < 2; ++g)
#pragma unroll
    for (int td = 0; td < 4; ++td) acc[g][td] = (f32x4){0.f, 0.f, 0.f, 0.f};
  float lg0 = 0.f, lg1 = 0.f;

  // K staging: thread owns key-pair (2kp,2kp+1), d-cols d0..d0+7 (from xbf)
  const int kp = tid >> 3;             // 0..31
  const int d0 = (tid & 7) * 8;        // 0,8,...,56
  const __bf16* kbase = xb + (size_t)(2 * kp) * E_ + d0;
  // V staging: thread owns d-rows dv, dv+32, keys kv..kv+7 (from xbfT)
  const int dv = tid >> 3;             // 0..31
  const int kv = (tid & 7) * 8;        // 0,8,...,56
  const __bf16* vbase = xbfT + ((size_t)(bh * DK_ + dv)) * T_ + kv;

  // swizzled VtF byte offsets (consts per thread)
  const int rotA = ((dv & 7) ^ ((dv >> 3) & 7)) << 4;
  const int dvB = dv + 32;
  const int rotB = ((dvB & 7) ^ ((dvB >> 3) & 7)) << 4;
  const int vbyteA = dv * 128 + ((kv * 2) ^ rotA);
  const int vbyteB = dvB * 128 + ((kv * 2) ^ rotB);

  // ---- prologue: load + stage tile 0 into buf 0 ----
  {
    uint4 k0 = *reinterpret_cast<const uint4*>(kbase);
    uint4 k1 = *reinterpret_cast<const uint4*>(kbase + E_);
    uint4 v0 = *reinterpret_cast<const uint4*>(vbase);
    uint4 v1 = *reinterpret_cast<const uint4*>(vbase + (size_t)32 * T_);
    *reinterpret_cast<uint4*>(&Kt[0][2 * kp][d0])     = k0;
    *reinterpret_cast<uint4*>(&Kt[0][2 * kp + 1][d0]) = k1;
    char* vb = reinterpret_cast<char*>(&VtF[0][0]);
    *reinterpret_cast<uint4*>(vb + vbyteA) = v0;
    *reinterpret_cast<uint4*>(vb + vbyteB) = v1;
  }
  __syncthreads();

  for (int t = 0; t < NT_; ++t) {
    const int cur = t & 1;
    const __bf16* Ktc = &Kt[cur][0][0];
    const char*   Vtc = reinterpret_cast<const char*>(&VtF[cur][0]);

    // ---- T14: issue next tile's global loads FIRST ----
    uint4 nk0, nk1, nv0, nv1;
    const bool have_next = (t + 1 < NT_);
    if (have_next) {
      const __bf16* nk = kbase + (size_t)(t + 1) * KVBLK * E_;
      const __bf16* nv = vbase + (size_t)(t + 1) * KVBLK;
      nk0 = *reinterpret_cast<const uint4*>(nk);
      nk1 = *reinterpret_cast<const uint4*>(nk + E_);
      nv0 = *reinterpret_cast<const uint4*>(nv);
      nv1 = *reinterpret_cast<const uint4*>(nv + (size_t)32 * T_);
    }

    // ---- S^T = K Q'^T for both q-groups (K frags shared) ----
    f32x4 s0[4], s1[4];
    __builtin_amdgcn_s_setprio(1);
#pragma unroll
    for (int tn = 0; tn < 4; ++tn) {
      const __bf16* kr = Ktc + (tn * 16 + l16) * (DK_ + 8);
      bf16x8 ka0 = *reinterpret_cast<const bf16x8*>(kr + lhi * 8);
      bf16x8 ka1 = *reinterpret_cast<const bf16x8*>(kr + 32 + lhi * 8);
      f32x4 c0 = (f32x4){0.f, 0.f, 0.f, 0.f};
      c0 = __builtin_amdgcn_mfma_f32_16x16x32_bf16(ka0, qa[0][0], c0, 0, 0, 0);
      c0 = __builtin_amdgcn_mfma_f32_16x16x32_bf16(ka1, qa[0][1], c0, 0, 0, 0);
      s0[tn] = c0;
      f32x4 c1 = (f32x4){0.f, 0.f, 0.f, 0.f};
      c1 = __builtin_amdgcn_mfma_f32_16x16x32_bf16(ka0, qa[1][0], c1, 0, 0, 0);
      c1 = __builtin_amdgcn_mfma_f32_16x16x32_bf16(ka1, qa[1][1], c1, 0, 0, 0);
      s1[tn] = c1;
    }
    __builtin_amdgcn_s_setprio(0);

    // ---- static-max softmax: p = exp2(s), pack via cvt_pk, b64 writes ----
#pragma unroll
    for (int tn = 0; tn < 4; ++tn) {
      float p0 = __builtin_exp2f(s0[tn][0]), p1 = __builtin_exp2f(s0[tn][1]);
      float p2 = __builtin_exp2f(s0[tn][2]), p3 = __builtin_exp2f(s0[tn][3]);
      lg0 += (p0 + p1) + (p2 + p3);
      uint2 w; w.x = pk2(p0, p1); w.y = pk2(p2, p3);
      *reinterpret_cast<uint2*>(&Pl[wave][l16][tn * 16 + lhi * 4]) = w;
      float q0 = __builtin_exp2f(s1[tn][0]), q1 = __builtin_exp2f(s1[tn][1]);
      float q2 = __builtin_exp2f(s1[tn][2]), q3 = __builtin_exp2f(s1[tn][3]);
      lg1 += (q0 + q1) + (q2 + q3);
      uint2 u; u.x = pk2(q0, q1); u.y = pk2(q2, q3);
      *reinterpret_cast<uint2*>(&Pl[wave][16 + l16][tn * 16 + lhi * 4]) = u;
    }
    asm volatile("s_waitcnt lgkmcnt(0)" ::: "memory");  // wave-local P ready

    // ---- O += P V (V frags shared across q-groups) ----
    __builtin_amdgcn_s_setprio(1);
#pragma unroll
    for (int kb = 0; kb < 2; ++kb) {
      bf16x8 pa0 = *reinterpret_cast<const bf16x8*>(&Pl[wave][l16][kb * 32 + lhi * 8]);
      bf16x8 pa1 = *reinterpret_cast<const bf16x8*>(&Pl[wave][16 + l16][kb * 32 + lhi * 8]);
#pragma unroll
      for (int td = 0; td < 4; ++td) {
        const int d = td * 16 + l16;
        const int byte = d * 128 +
                         ((kb * 64 + lhi * 16) ^ (((d & 7) ^ ((d >> 3) & 7)) << 4));
        bf16x8 vv = *reinterpret_cast<const bf16x8*>(Vtc + byte);
        acc[0][td] = __builtin_amdgcn_mfma_f32_16x16x32_bf16(pa0, vv, acc[0][td], 0, 0, 0);
        acc[1][td] = __builtin_amdgcn_mfma_f32_16x16x32_bf16(pa1, vv, acc[1][td], 0, 0, 0);
      }
    }
    __builtin_amdgcn_s_setprio(0);

    // ---- T14 write-late: stage tile t+1 into buf cur^1 (pure b128 copies) ----
    if (have_next) {
      const int nxt = cur ^ 1;
      *reinterpret_cast<uint4*>(&Kt[nxt][2 * kp][d0])     = nk0;
      *reinterpret_cast<uint4*>(&Kt[nxt][2 * kp + 1][d0]) = nk1;
      char* vb = reinterpret_cast<char*>(&VtF[nxt][0]);
      *reinterpret_cast<uint4*>(vb + vbyteA) = nv0;
      *reinterpret_cast<uint4*>(vb + vbyteB) = nv1;
    }
    __syncthreads();   // single barrier: buf[cur^1] staged, buf[cur] reads done
  }

  // ---- epilogue: finish l, redistribute, write O/l ----
  lg0 += __shfl_xor(lg0, 16); lg0 += __shfl_xor(lg0, 32);
  lg1 += __shfl_xor(lg1, 16); lg1 += __shfl_xor(lg1, 32);
  float inv0[4], inv1[4];
#pragma unroll
  for (int i = 0; i < 4; ++i) {
    inv0[i] = 1.f / __shfl(lg0, lhi * 4 + i);
    inv1[i] = 1.f / __shfl(lg1, lhi * 4 + i);
  }
#pragma unroll
  for (int td = 0; td < 4; ++td)
#pragma unroll
    for (int i = 0; i < 4; ++i) {
      const int col = h * DK_ + td * 16 + l16;
      const size_t r0 = (size_t)b * T_ + qbase + wave * 32 + lhi * 4 + i;
      out[r0 * E_ + col]        = acc[0][td][i] * inv0[i];
      out[(r0 + 16) * E_ + col] = acc[1][td][i] * inv1[i];
    }
}

// ---------------------------------------------------------------------------
// Kernel 3: out = LN2( LN1(x + attn) + ffn_c ), in-place on d_out.
// ---------------------------------------------------------------------------
__device__ __forceinline__ float block_sum(float v, float* redrow, int lane, int wave) {
#pragma unroll
  for (int off = 1; off < 64; off <<= 1) v += __shfl_xor(v, off);
  if (lane == 0) redrow[wave] = v;
  __syncthreads();
  return redrow[0] + redrow[1] + redrow[2] + redrow[3];
}

__global__ __launch_bounds__(256)
void ln_kernel(const float* __restrict__ x, const float* __restrict__ ffn_c,
               const float* __restrict__ g1, const float* __restrict__ be1,
               const float* __restrict__ g2, const float* __restrict__ be2,
               float* io) {
  __shared__ float red[4][4];
  const int row = blockIdx.x;
  const int tid = threadIdx.x;
  const int lane = tid & 63, wave = tid >> 6;
  const float* xr = x + (size_t)row * E_;
  float* ior = io + (size_t)row * E_;

  float4 xv = reinterpret_cast<const float4*>(xr)[tid];
  float4 av = reinterpret_cast<const float4*>(ior)[tid];
  float v[4] = {xv.x + av.x, xv.y + av.y, xv.z + av.z, xv.w + av.w};

  float mu1 = block_sum(v[0] + v[1] + v[2] + v[3], red[0], lane, wave) * (1.f / E_);
  float q1 = 0.f;
#pragma unroll
  for (int j = 0; j < 4; ++j) { float d = v[j] - mu1; q1 += d * d; }
  float var1 = block_sum(q1, red[1], lane, wave) * (1.f / E_);
  float rs1 = rsqrtf(var1 + 1e-5f);

  const int e0 = tid * 4;
  float y[4];
#pragma unroll
  for (int j = 0; j < 4; ++j)
    y[j] = (v[j] - mu1) * rs1 * g1[e0 + j] + be1[e0 + j] + ffn_c[e0 + j];

  float mu2 = block_sum(y[0] + y[1] + y[2] + y[3], red[2], lane, wave) * (1.f / E_);
  float q2 = 0.f;
#pragma unroll
  for (int j = 0; j < 4; ++j) { float d = y[j] - mu2; q2 += d * d; }
  float var2 = block_sum(q2, red[3], lane, wave) * (1.f / E_);
  float rs2 = rsqrtf(var2 + 1e-5f);

  float4 o;
  o.x = (y[0] - mu2) * rs2 * g2[e0 + 0] + be2[e0 + 0];
  o.y = (y[1] - mu2) * rs2 * g2[e0 + 1] + be2[e0 + 1];
  o.z = (y[2] - mu2) * rs2 * g2[e0 + 2] + be2[e0 + 2];
  o.w = (y[3] - mu2) * rs2 * g2[e0 + 3] + be2[e0 + 3];
  reinterpret_cast<float4*>(ior)[tid] = o;
}

// ---------------------------------------------------------------------------
extern "C" void kernel_launch(void* const* d_in, const int* in_sizes, int n_in,
                              void* d_out, int out_size, void* d_ws, size_t ws_size,
                              hipStream_t stream) {
  (void)in_sizes; (void)n_in; (void)out_size; (void)ws_size;
  const float* x     = (const float*)d_in[0];
  const float* q_out = (const float*)d_in[2];
  const float* w1    = (const float*)d_in[3];
  const float* b1    = (const float*)d_in[4];
  const float* w2    = (const float*)d_in[5];
  const float* b2    = (const float*)d_in[6];
  const float* g1    = (const float*)d_in[7];
  const float* be1   = (const float*)d_in[8];
  const float* g2    = (const float*)d_in[9];
  const float* be2   = (const float*)d_in[10];
  float* out   = (float*)d_out;

  float* ffn_c = (float*)d_ws;                               // E_ floats
  float* part  = ffn_c + E_;                                 // NPART*E_ floats
  __bf16* xbf  = (__bf16*)(part + (size_t)NPART * E_);       // 8.4 MB
  __bf16* xbfT = xbf + (size_t)B_ * T_ * E_;                 // 8.4 MB

  prep_kernel<<<CVT_BLOCKS + NPART, 256, 0, stream>>>(x, xbf, xbfT, q_out, w1,
                                                      b1, w2, part);
  ffn_reduce_kernel<<<E_ / 256, 256, 0, stream>>>(part, b2, ffn_c);
  dim3 ag(T_ / QBLK, B_ * H_);
  attn_kernel<<<ag, 256, 0, stream>>>(xbf, xbfT, out);
  ln_kernel<<<B_ * T_, 256, 0, stream>>>(x, ffn_c, g1, be1, g2, be2, out);
}

// Round 23
// 89.937 us; speedup vs baseline: 1.1314x; 1.1314x over previous
//
#include <hip/hip_runtime.h>

#define E_   1024
#define H_   16
#define DK_  64
#define FFN_ 4096
#define NQ_  8
#define B_   2
#define T_   2048
#define QBLK 128
#define KVBLK 64
#define NT_  (T_ / KVBLK)

#define NPART 256
#define ROWS_PER_PART (FFN_ / NPART)   // 16
#define CVT_BLOCKS (B_ * (T_ / 64) * H_)   // 1024

typedef __attribute__((ext_vector_type(8))) __bf16 bf16x8;
typedef __attribute__((ext_vector_type(4))) float f32x4;

__device__ __forceinline__ __bf16 tobf(float f) { return (__bf16)f; }

__device__ __forceinline__ unsigned pk2(float a, float b) {
  union { __bf16 h; unsigned short u; } ua, ub;
  ua.h = (__bf16)a; ub.h = (__bf16)b;
  return (unsigned)ua.u | ((unsigned)ub.u << 16);
}

// ---------------------------------------------------------------------------
// Kernel 0 (fat): blocks [0,1024): convert+transpose x -> xbf, xbfT;
//                 blocks [1024,1280): ffn_part (const-FFN split-K partials).
// ---------------------------------------------------------------------------
__global__ __launch_bounds__(256)
void prep_kernel(const float* __restrict__ x, __bf16* __restrict__ xbf,
                 __bf16* __restrict__ xbfT,
                 const float* __restrict__ q_out, const float* __restrict__ w1,
                 const float* __restrict__ b1, const float* __restrict__ w2,
                 float* __restrict__ part) {
  const int tid = threadIdx.x;
  if (blockIdx.x < CVT_BLOCKS) {
    __shared__ __bf16 tile[64][66];
    const int bid = blockIdx.x;
    const int h  = bid & 15;
    const int tt = (bid >> 4) & 31;
    const int b  = bid >> 9;
    const float* src = x + ((size_t)(b * T_ + tt * 64)) * E_ + h * 64;
#pragma unroll
    for (int u = 0; u < 2; ++u) {
      const int idx = tid + 256 * u;
      const int r = idx >> 3;
      const int c = (idx & 7) * 8;
      float4 f0 = *reinterpret_cast<const float4*>(src + (size_t)r * E_ + c);
      float4 f1 = *reinterpret_cast<const float4*>(src + (size_t)r * E_ + c + 4);
      bf16x8 v;
      v[0] = tobf(f0.x); v[1] = tobf(f0.y); v[2] = tobf(f0.z); v[3] = tobf(f0.w);
      v[4] = tobf(f1.x); v[5] = tobf(f1.y); v[6] = tobf(f1.z); v[7] = tobf(f1.w);
      *reinterpret_cast<bf16x8*>(
          &xbf[((size_t)(b * T_ + tt * 64 + r)) * E_ + h * 64 + c]) = v;
#pragma unroll
      for (int j = 0; j < 8; ++j) tile[r][c + j] = v[j];
    }
    __syncthreads();
#pragma unroll
    for (int u = 0; u < 2; ++u) {
      const int idx = tid + 256 * u;
      const int d  = idx >> 3;
      const int tc = (idx & 7) * 8;
      bf16x8 v;
#pragma unroll
      for (int j = 0; j < 8; ++j) v[j] = tile[tc + j][d];
      *reinterpret_cast<bf16x8*>(
          &xbfT[((size_t)((b * H_ + h) * DK_ + d)) * T_ + tt * 64 + tc]) = v;
    }
  } else {
    __shared__ float hbuf[ROWS_PER_PART];
    const int p = blockIdx.x - CVT_BLOCKS;
    const int f0 = p * ROWS_PER_PART;
    if (tid < ROWS_PER_PART) {
      const int f = f0 + tid;
      float a = b1[f];
#pragma unroll
      for (int n = 0; n < NQ_; ++n) a += q_out[n] * w1[n * FFN_ + f];
      hbuf[tid] = fmaxf(a, 0.f);
    }
    __syncthreads();
    float4 acc = {0.f, 0.f, 0.f, 0.f};
#pragma unroll
    for (int j = 0; j < ROWS_PER_PART; ++j) {
      const float hf = hbuf[j];
      float4 w = reinterpret_cast<const float4*>(w2 + (size_t)(f0 + j) * E_)[tid];
      acc.x += hf * w.x; acc.y += hf * w.y; acc.z += hf * w.z; acc.w += hf * w.w;
    }
    reinterpret_cast<float4*>(part + (size_t)p * E_)[tid] = acc;
  }
}

__global__ __launch_bounds__(256)
void ffn_reduce_kernel(const float* __restrict__ part, const float* __restrict__ b2,
                       float* __restrict__ ffn_c) {
  const int e = blockIdx.x * 256 + threadIdx.x;
  float a = b2[e];
  for (int r = 0; r < NPART; ++r) a += part[(size_t)r * E_ + e];
  ffn_c[e] = a;
}

// ---------------------------------------------------------------------------
// Kernel 2: flash attention (r16 verbatim — best verified: 71.9 us).
// Swapped QK^T, G=2 (32 q-rows/wave), Kt+VtF double-buffered (1 barrier/
// tile), V staged from xbfT (pure b128 copies), T14 issue-early/write-late,
// setprio.  grid = (T/128, B*H) x 256 thr.
// ---------------------------------------------------------------------------
__global__ __launch_bounds__(256)
void attn_kernel(const __bf16* __restrict__ xbf, const __bf16* __restrict__ xbfT,
                 float* __restrict__ out) {
  __shared__ __bf16 Kt[2][KVBLK][DK_ + 8];   // [buf][key][d]
  __shared__ __bf16 VtF[2][DK_ * KVBLK];     // [buf][d][key], byte^=(rot(d)<<4)
  __shared__ __bf16 Pl[4][32][DK_ + 8];      // per-wave P [qrow 0..31][key]

  const int tid  = threadIdx.x;
  const int wave = tid >> 6;
  const int lane = tid & 63;
  const int l16  = lane & 15;
  const int lhi  = lane >> 4;          // 0..3

  const int bh = blockIdx.y;
  const int b  = bh >> 4;
  const int h  = bh & 15;
  const int qbase = blockIdx.x * QBLK;
  const __bf16* xb = xbf + (size_t)b * T_ * E_ + h * DK_;

  // Q B-frags for 2 groups of 16 rows, pre-scaled by 1/8 (exact in bf16)
  bf16x8 qa[2][2];
  {
    const __bf16 sc = (__bf16)0.125f;
#pragma unroll
    for (int g = 0; g < 2; ++g) {
      const __bf16* qrow = xb + (size_t)(qbase + wave * 32 + g * 16 + l16) * E_;
      bf16x8 v0 = *reinterpret_cast<const bf16x8*>(qrow + lhi * 8);
      bf16x8 v1 = *reinterpret_cast<const bf16x8*>(qrow + 32 + lhi * 8);
#pragma unroll
      for (int j = 0; j < 8; ++j) { v0[j] *= sc; v1[j] *= sc; }
      qa[g][0] = v0; qa[g][1] = v1;
    }
  }

  f32x4 acc[2][4];
#pragma unroll
  for (int g = 0; g < 2; ++g)
#pragma unroll
    for (int td = 0; td < 4; ++td) acc[g][td] = (f32x4){0.f, 0.f, 0.f, 0.f};
  float lg0 = 0.f, lg1 = 0.f;

  // K staging: thread owns key-pair (2kp,2kp+1), d-cols d0..d0+7 (from xbf)
  const int kp = tid >> 3;             // 0..31
  const int d0 = (tid & 7) * 8;        // 0,8,...,56
  const __bf16* kbase = xb + (size_t)(2 * kp) * E_ + d0;
  // V staging: thread owns d-rows dv, dv+32, keys kv..kv+7 (from xbfT)
  const int dv = tid >> 3;             // 0..31
  const int kv = (tid & 7) * 8;        // 0,8,...,56
  const __bf16* vbase = xbfT + ((size_t)(bh * DK_ + dv)) * T_ + kv;

  // swizzled VtF byte offsets (consts per thread)
  const int rotA = ((dv & 7) ^ ((dv >> 3) & 7)) << 4;
  const int dvB = dv + 32;
  const int rotB = ((dvB & 7) ^ ((dvB >> 3) & 7)) << 4;
  const int vbyteA = dv * 128 + ((kv * 2) ^ rotA);
  const int vbyteB = dvB * 128 + ((kv * 2) ^ rotB);

  // ---- prologue: load + stage tile 0 into buf 0 ----
  {
    uint4 k0 = *reinterpret_cast<const uint4*>(kbase);
    uint4 k1 = *reinterpret_cast<const uint4*>(kbase + E_);
    uint4 v0 = *reinterpret_cast<const uint4*>(vbase);
    uint4 v1 = *reinterpret_cast<const uint4*>(vbase + (size_t)32 * T_);
    *reinterpret_cast<uint4*>(&Kt[0][2 * kp][d0])     = k0;
    *reinterpret_cast<uint4*>(&Kt[0][2 * kp + 1][d0]) = k1;
    char* vb = reinterpret_cast<char*>(&VtF[0][0]);
    *reinterpret_cast<uint4*>(vb + vbyteA) = v0;
    *reinterpret_cast<uint4*>(vb + vbyteB) = v1;
  }
  __syncthreads();

  for (int t = 0; t < NT_; ++t) {
    const int cur = t & 1;
    const __bf16* Ktc = &Kt[cur][0][0];
    const char*   Vtc = reinterpret_cast<const char*>(&VtF[cur][0]);

    // ---- T14: issue next tile's global loads FIRST ----
    uint4 nk0, nk1, nv0, nv1;
    const bool have_next = (t + 1 < NT_);
    if (have_next) {
      const __bf16* nk = kbase + (size_t)(t + 1) * KVBLK * E_;
      const __bf16* nv = vbase + (size_t)(t + 1) * KVBLK;
      nk0 = *reinterpret_cast<const uint4*>(nk);
      nk1 = *reinterpret_cast<const uint4*>(nk + E_);
      nv0 = *reinterpret_cast<const uint4*>(nv);
      nv1 = *reinterpret_cast<const uint4*>(nv + (size_t)32 * T_);
    }

    // ---- S^T = K (Q/8)^T for both q-groups (K frags shared) ----
    f32x4 s0[4], s1[4];
    __builtin_amdgcn_s_setprio(1);
#pragma unroll
    for (int tn = 0; tn < 4; ++tn) {
      const __bf16* kr = Ktc + (tn * 16 + l16) * (DK_ + 8);
      bf16x8 ka0 = *reinterpret_cast<const bf16x8*>(kr + lhi * 8);
      bf16x8 ka1 = *reinterpret_cast<const bf16x8*>(kr + 32 + lhi * 8);
      f32x4 c0 = (f32x4){0.f, 0.f, 0.f, 0.f};
      c0 = __builtin_amdgcn_mfma_f32_16x16x32_bf16(ka0, qa[0][0], c0, 0, 0, 0);
      c0 = __builtin_amdgcn_mfma_f32_16x16x32_bf16(ka1, qa[0][1], c0, 0, 0, 0);
      s0[tn] = c0;
      f32x4 c1 = (f32x4){0.f, 0.f, 0.f, 0.f};
      c1 = __builtin_amdgcn_mfma_f32_16x16x32_bf16(ka0, qa[1][0], c1, 0, 0, 0);
      c1 = __builtin_amdgcn_mfma_f32_16x16x32_bf16(ka1, qa[1][1], c1, 0, 0, 0);
      s1[tn] = c1;
    }
    __builtin_amdgcn_s_setprio(0);

    // ---- static-max softmax, row-wise P pack + b64 writes ----
#pragma unroll
    for (int tn = 0; tn < 4; ++tn) {
      float p0 = __expf(s0[tn][0]), p1 = __expf(s0[tn][1]);
      float p2 = __expf(s0[tn][2]), p3 = __expf(s0[tn][3]);
      lg0 += (p0 + p1) + (p2 + p3);
      uint2 w; w.x = pk2(p0, p1); w.y = pk2(p2, p3);
      *reinterpret_cast<uint2*>(&Pl[wave][l16][tn * 16 + lhi * 4]) = w;
      float q0 = __expf(s1[tn][0]), q1 = __expf(s1[tn][1]);
      float q2 = __expf(s1[tn][2]), q3 = __expf(s1[tn][3]);
      lg1 += (q0 + q1) + (q2 + q3);
      uint2 u; u.x = pk2(q0, q1); u.y = pk2(q2, q3);
      *reinterpret_cast<uint2*>(&Pl[wave][16 + l16][tn * 16 + lhi * 4]) = u;
    }
    asm volatile("s_waitcnt lgkmcnt(0)" ::: "memory");  // wave-local P ready

    // ---- O += P V (V frags shared across q-groups) ----
    __builtin_amdgcn_s_setprio(1);
#pragma unroll
    for (int kb = 0; kb < 2; ++kb) {
      bf16x8 pa0 = *reinterpret_cast<const bf16x8*>(&Pl[wave][l16][kb * 32 + lhi * 8]);
      bf16x8 pa1 = *reinterpret_cast<const bf16x8*>(&Pl[wave][16 + l16][kb * 32 + lhi * 8]);
#pragma unroll
      for (int td = 0; td < 4; ++td) {
        const int d = td * 16 + l16;
        const int byte = d * 128 +
                         ((kb * 64 + lhi * 16) ^ (((d & 7) ^ ((d >> 3) & 7)) << 4));
        bf16x8 vv = *reinterpret_cast<const bf16x8*>(Vtc + byte);
        acc[0][td] = __builtin_amdgcn_mfma_f32_16x16x32_bf16(pa0, vv, acc[0][td], 0, 0, 0);
        acc[1][td] = __builtin_amdgcn_mfma_f32_16x16x32_bf16(pa1, vv, acc[1][td], 0, 0, 0);
      }
    }
    __builtin_amdgcn_s_setprio(0);

    // ---- T14 write-late: stage tile t+1 into buf cur^1 (pure b128 copies) ----
    if (have_next) {
      const int nxt = cur ^ 1;
      *reinterpret_cast<uint4*>(&Kt[nxt][2 * kp][d0])     = nk0;
      *reinterpret_cast<uint4*>(&Kt[nxt][2 * kp + 1][d0]) = nk1;
      char* vb = reinterpret_cast<char*>(&VtF[nxt][0]);
      *reinterpret_cast<uint4*>(vb + vbyteA) = nv0;
      *reinterpret_cast<uint4*>(vb + vbyteB) = nv1;
    }
    __syncthreads();   // single barrier: buf[cur^1] staged, buf[cur] reads done
  }

  // ---- epilogue: finish l, redistribute, write O/l ----
  lg0 += __shfl_xor(lg0, 16); lg0 += __shfl_xor(lg0, 32);
  lg1 += __shfl_xor(lg1, 16); lg1 += __shfl_xor(lg1, 32);
  float inv0[4], inv1[4];
#pragma unroll
  for (int i = 0; i < 4; ++i) {
    inv0[i] = 1.f / __shfl(lg0, lhi * 4 + i);
    inv1[i] = 1.f / __shfl(lg1, lhi * 4 + i);
  }
#pragma unroll
  for (int td = 0; td < 4; ++td)
#pragma unroll
    for (int i = 0; i < 4; ++i) {
      const int col = h * DK_ + td * 16 + l16;
      const size_t r0 = (size_t)b * T_ + qbase + wave * 32 + lhi * 4 + i;
      out[r0 * E_ + col]        = acc[0][td][i] * inv0[i];
      out[(r0 + 16) * E_ + col] = acc[1][td][i] * inv1[i];
    }
}

// ---------------------------------------------------------------------------
// Kernel 3: out = LN2( LN1(x + attn) + ffn_c ), in-place on d_out.
// ---------------------------------------------------------------------------
__device__ __forceinline__ float block_sum(float v, float* redrow, int lane, int wave) {
#pragma unroll
  for (int off = 1; off < 64; off <<= 1) v += __shfl_xor(v, off);
  if (lane == 0) redrow[wave] = v;
  __syncthreads();
  return redrow[0] + redrow[1] + redrow[2] + redrow[3];
}

__global__ __launch_bounds__(256)
void ln_kernel(const float* __restrict__ x, const float* __restrict__ ffn_c,
               const float* __restrict__ g1, const float* __restrict__ be1,
               const float* __restrict__ g2, const float* __restrict__ be2,
               float* io) {
  __shared__ float red[4][4];
  const int row = blockIdx.x;
  const int tid = threadIdx.x;
  const int lane = tid & 63, wave = tid >> 6;
  const float* xr = x + (size_t)row * E_;
  float* ior = io + (size_t)row * E_;

  float4 xv = reinterpret_cast<const float4*>(xr)[tid];
  float4 av = reinterpret_cast<const float4*>(ior)[tid];
  float v[4] = {xv.x + av.x, xv.y + av.y, xv.z + av.z, xv.w + av.w};

  float mu1 = block_sum(v[0] + v[1] + v[2] + v[3], red[0], lane, wave) * (1.f / E_);
  float q1 = 0.f;
#pragma unroll
  for (int j = 0; j < 4; ++j) { float d = v[j] - mu1; q1 += d * d; }
  float var1 = block_sum(q1, red[1], lane, wave) * (1.f / E_);
  float rs1 = rsqrtf(var1 + 1e-5f);

  const int e0 = tid * 4;
  float y[4];
#pragma unroll
  for (int j = 0; j < 4; ++j)
    y[j] = (v[j] - mu1) * rs1 * g1[e0 + j] + be1[e0 + j] + ffn_c[e0 + j];

  float mu2 = block_sum(y[0] + y[1] + y[2] + y[3], red[2], lane, wave) * (1.f / E_);
  float q2 = 0.f;
#pragma unroll
  for (int j = 0; j < 4; ++j) { float d = y[j] - mu2; q2 += d * d; }
  float var2 = block_sum(q2, red[3], lane, wave) * (1.f / E_);
  float rs2 = rsqrtf(var2 + 1e-5f);

  float4 o;
  o.x = (y[0] - mu2) * rs2 * g2[e0 + 0] + be2[e0 + 0];
  o.y = (y[1] - mu2) * rs2 * g2[e0 + 1] + be2[e0 + 1];
  o.z = (y[2] - mu2) * rs2 * g2[e0 + 2] + be2[e0 + 2];
  o.w = (y[3] - mu2) * rs2 * g2[e0 + 3] + be2[e0 + 3];
  reinterpret_cast<float4*>(ior)[tid] = o;
}

// ---------------------------------------------------------------------------
extern "C" void kernel_launch(void* const* d_in, const int* in_sizes, int n_in,
                              void* d_out, int out_size, void* d_ws, size_t ws_size,
                              hipStream_t stream) {
  (void)in_sizes; (void)n_in; (void)out_size; (void)ws_size;
  const float* x     = (const float*)d_in[0];
  const float* q_out = (const float*)d_in[2];
  const float* w1    = (const float*)d_in[3];
  const float* b1    = (const float*)d_in[4];
  const float* w2    = (const float*)d_in[5];
  const float* b2    = (const float*)d_in[6];
  const float* g1    = (const float*)d_in[7];
  const float* be1   = (const float*)d_in[8];
  const float* g2    = (const float*)d_in[9];
  const float* be2   = (const float*)d_in[10];
  float* out   = (float*)d_out;

  float* ffn_c = (float*)d_ws;                               // E_ floats
  float* part  = ffn_c + E_;                                 // NPART*E_ floats
  __bf16* xbf  = (__bf16*)(part + (size_t)NPART * E_);       // 8.4 MB
  __bf16* xbfT = xbf + (size_t)B_ * T_ * E_;                 // 8.4 MB

  prep_kernel<<<CVT_BLOCKS + NPART, 256, 0, stream>>>(x, xbf, xbfT, q_out, w1,
                                                      b1, w2, part);
  ffn_reduce_kernel<<<E_ / 256, 256, 0, stream>>>(part, b2, ffn_c);
  dim3 ag(T_ / QBLK, B_ * H_);
  attn_kernel<<<ag, 256, 0, stream>>>(xbf, xbfT, out);
  ln_kernel<<<B_ * T_, 256, 0, stream>>>(x, ffn_c, g1, be1, g2, be2, out);
}